// Round 6
// baseline (126.066 us; speedup 1.0000x reference)
//
#include <hip/hip_runtime.h>
#include <hip/hip_bf16.h>

#define NB 16
#define SQ 2048
#define SK 2048
#define DH 64
#define RS 72          // LDS row stride in halfwords (144 B)
#define NKT (SK / 64)  // 32 key tiles of 64

#define KBLK 1024      // prepass blocks for K convert
#define VBLK 512       // prepass blocks for V transpose
#define BBLK 128       // prepass blocks for bias

typedef __attribute__((ext_vector_type(8))) short short8;
typedef __attribute__((ext_vector_type(8))) __bf16 bf16x8;
typedef __attribute__((ext_vector_type(4))) float floatx4;
typedef __attribute__((ext_vector_type(2))) unsigned uint2v;

__device__ __forceinline__ unsigned pk2(float a, float b) {
  __hip_bfloat162 h = __float22bfloat162_rn(make_float2(a, b));
  unsigned u; __builtin_memcpy(&u, &h, 4); return u;
}
__device__ __forceinline__ floatx4 mfma16(short8 a, short8 b, floatx4 c) {
  return __builtin_amdgcn_mfma_f32_16x16x32_bf16(
      __builtin_bit_cast(bf16x8, a), __builtin_bit_cast(bf16x8, b), c, 0, 0, 0);
}

// ---------- fused prepass: K->bf16, V->bf16 transposed tile-packed, mask->bias ----------
__global__ __launch_bounds__(256)
void prepass(const float* __restrict__ K, const float* __restrict__ V,
             const int* __restrict__ m, short* __restrict__ Kb,
             short* __restrict__ Vt, float* __restrict__ bias) {
  __shared__ unsigned tlw[64 * 33];   // [d][keypair], word-packed, +1 pad
  const int blk = blockIdx.x;
  const int t = threadIdx.x;
  if (blk < KBLK) {
    size_t i8 = ((size_t)blk * 256 + t) * 8;
    floatx4 a = *(const floatx4*)(K + i8);
    floatx4 b = *(const floatx4*)(K + i8 + 4);
    union { unsigned u[4]; short8 s; } w;
    w.u[0] = pk2(a[0], a[1]); w.u[1] = pk2(a[2], a[3]);
    w.u[2] = pk2(b[0], b[1]); w.u[3] = pk2(b[2], b[3]);
    *(short8*)(Kb + i8) = w.s;
  } else if (blk < KBLK + VBLK) {
    const int bt = blk - KBLK;            // b*32 + kt
    const int key2 = t & 31;              // key pair -> keys 2*key2, 2*key2+1
    const int dg = (t >> 5) * 8;          // 0,8,...,56
    const float* vp0 = V + ((size_t)bt * 64 + 2 * key2) * 64 + dg;
    const float* vp1 = vp0 + 64;
    floatx4 va  = *(const floatx4*)(vp0);
    floatx4 va2 = *(const floatx4*)(vp0 + 4);
    floatx4 vb  = *(const floatx4*)(vp1);
    floatx4 vb2 = *(const floatx4*)(vp1 + 4);
#pragma unroll
    for (int j = 0; j < 4; ++j) {
      tlw[(dg + j) * 33 + key2]     = pk2(va[j],  vb[j]);
      tlw[(dg + 4 + j) * 33 + key2] = pk2(va2[j], vb2[j]);
    }
    __syncthreads();
    const short* tls = (const short*)tlw;
    short* dst = Vt + (size_t)bt * 4096;
#pragma unroll
    for (int i = 0; i < 2; ++i) {
      int idx = i * 2048 + t * 8;          // flat [d][key]
      int d = idx >> 6, key = idx & 63;
      *(short8*)(dst + idx) = *(const short8*)(tls + d * 66 + key);
    }
  } else {
    int i = (blk - KBLK - VBLK) * 256 + t;
    bias[i] = m[i] ? -1e30f : 0.0f;
  }
}

// ---------- main flash-attention kernel (split-K x2, transposed-S softmax) ----------
__global__ __launch_bounds__(256)
void attn_main(const float* __restrict__ Q, const short* __restrict__ Kb,
               const short* __restrict__ Vt, const float* __restrict__ bias,
               float* __restrict__ Out, float* __restrict__ Op1,
               float2* __restrict__ ml) {
  __shared__ __align__(16) short ks[64 * RS];
  __shared__ __align__(16) short vt[64 * RS];
  __shared__ __align__(16) short pb[4 * 16 * RS];

  const int half = blockIdx.x >> 9;
  const int rest = blockIdx.x & 511;
  const int b    = rest >> 5;
  const int qt   = rest & 31;
  const int tid  = threadIdx.x;
  const int lane = tid & 63;
  const int wave = tid >> 6;
  const int L    = lane & 15;
  const int quad = lane >> 4;
  const int q0w  = qt * 64 + wave * 16;
  const int kt0  = half << 4;

  const float QS = 0.125f * 1.4426950408889634f;
  short8 qf[2];
  {
    const float* qp = Q + ((size_t)b * SQ + q0w + L) * DH + 8 * quad;
#pragma unroll
    for (int c = 0; c < 2; ++c) {
      floatx4 a  = *(const floatx4*)(qp + 32 * c);
      floatx4 a2 = *(const floatx4*)(qp + 32 * c + 4);
      union { unsigned u[4]; short8 s; } w;
      w.u[0] = pk2(a[0] * QS, a[1] * QS);
      w.u[1] = pk2(a[2] * QS, a[3] * QS);
      w.u[2] = pk2(a2[0] * QS, a2[1] * QS);
      w.u[3] = pk2(a2[2] * QS, a2[3] * QS);
      qf[c] = w.s;
    }
  }

  floatx4 o[4];
#pragma unroll
  for (int n = 0; n < 4; ++n) o[n] = (floatx4){0.f, 0.f, 0.f, 0.f};
  float m_q = -1e30f, l_q = 0.f;

  short* pbw = pb + wave * 16 * RS;

  const short* kg = Kb + (size_t)b * SK * DH;
  const short* vg = Vt + (size_t)b * 32 * 4096;
  const float* bg = bias + b * SK;

  const int srow = tid >> 3;
  const int scol = (tid & 7) * 8;

  short8 kr[2], vr[2];
#pragma unroll
  for (int i = 0; i < 2; ++i) {
    kr[i] = *(const short8*)(kg + (size_t)kt0 * 4096 + i * 2048 + tid * 8);
    vr[i] = *(const short8*)(vg + (size_t)kt0 * 4096 + i * 2048 + tid * 8);
  }

  for (int kt = kt0; kt < kt0 + 16; ++kt) {
#pragma unroll
    for (int i = 0; i < 2; ++i) {
      int row = i * 32 + srow;
      *(short8*)(ks + row * RS + scol) = kr[i];
      *(short8*)(vt + row * RS + scol) = vr[i];
    }
    __syncthreads();

    if (kt + 1 < kt0 + 16) {
      const short* kn = kg + (size_t)(kt + 1) * 4096;
      const short* vn = vg + (size_t)(kt + 1) * 4096;
#pragma unroll
      for (int i = 0; i < 2; ++i) {
        kr[i] = *(const short8*)(kn + i * 2048 + tid * 8);
        vr[i] = *(const short8*)(vn + i * 2048 + tid * 8);
      }
    }

    // ---- S^T = K Q^T ----
    floatx4 s[4];
#pragma unroll
    for (int t = 0; t < 4; ++t) {
      short8 kf0 = *(short8*)(ks + (16 * t + L) * RS + quad * 8);
      short8 kf1 = *(short8*)(ks + (16 * t + L) * RS + 32 + quad * 8);
      floatx4 z = (floatx4){0.f, 0.f, 0.f, 0.f};
      s[t] = mfma16(kf0, qf[0], z);
      s[t] = mfma16(kf1, qf[1], s[t]);
    }

    const float* bq = bg + kt * 64 + 4 * quad;
    float a[4][4];
    float rm = -1e30f;
#pragma unroll
    for (int t = 0; t < 4; ++t) {
      floatx4 bv = *(const floatx4*)(bq + 16 * t);
#pragma unroll
      for (int r = 0; r < 4; ++r) {
        a[t][r] = s[t][r] + bv[r];
        rm = fmaxf(rm, a[t][r]);
      }
    }
    rm = fmaxf(rm, __shfl_xor(rm, 16));
    rm = fmaxf(rm, __shfl_xor(rm, 32));
    float mn = fmaxf(m_q, rm);
    float alpha_q = __builtin_amdgcn_exp2f(m_q - mn);
    m_q = mn;

    float rs = 0.f;
#pragma unroll
    for (int t = 0; t < 4; ++t) {
      float p0 = __builtin_amdgcn_exp2f(a[t][0] - mn);
      float p1 = __builtin_amdgcn_exp2f(a[t][1] - mn);
      float p2 = __builtin_amdgcn_exp2f(a[t][2] - mn);
      float p3 = __builtin_amdgcn_exp2f(a[t][3] - mn);
      rs += (p0 + p1) + (p2 + p3);
      uint2v w; w.x = pk2(p0, p1); w.y = pk2(p2, p3);
      *(uint2v*)(pbw + L * RS + 16 * t + 4 * quad) = w;
    }
    rs += __shfl_xor(rs, 16);
    rs += __shfl_xor(rs, 32);
    l_q = alpha_q * l_q + rs;

    float av[4];
#pragma unroll
    for (int r = 0; r < 4; ++r) av[r] = __shfl(alpha_q, quad * 4 + r);
#pragma unroll
    for (int n = 0; n < 4; ++n)
#pragma unroll
      for (int r = 0; r < 4; ++r) o[n][r] *= av[r];

    short8 pf0 = *(short8*)(pbw + L * RS + quad * 8);
    short8 pf1 = *(short8*)(pbw + L * RS + 32 + quad * 8);

#pragma unroll
    for (int n = 0; n < 4; ++n) {
      short8 vf0 = *(short8*)(vt + (16 * n + L) * RS + quad * 8);
      short8 vf1 = *(short8*)(vt + (16 * n + L) * RS + 32 + quad * 8);
      o[n] = mfma16(pf0, vf0, o[n]);
      o[n] = mfma16(pf1, vf1, o[n]);
    }
    __syncthreads();
  }

  // ---- epilogue: store UNNORMALIZED partial O and per-query (m,l) ----
  float* Od = half ? Op1 : Out;
#pragma unroll
  for (int r = 0; r < 4; ++r) {
    size_t row = (size_t)b * SQ + q0w + quad * 4 + r;
#pragma unroll
    for (int n = 0; n < 4; ++n)
      Od[row * DH + 16 * n + L] = o[n][r];
  }
  if (lane < 16)
    ml[((size_t)half * NB + b) * SQ + q0w + lane] = make_float2(m_q, l_q);
}

// ---------- combine the two split-K halves ----------
__global__ __launch_bounds__(256)
void combine(const float* __restrict__ Op1, const float2* __restrict__ ml,
             float* __restrict__ Out) {
  int idx = blockIdx.x * 256 + threadIdx.x;   // 0..262143
  int q = idx >> 3;
  int dc = (idx & 7) * 8;
  float2 s0 = ml[q];
  float2 s1 = ml[NB * SQ + q];
  float M = fmaxf(s0.x, s1.x);
  float w0 = __builtin_amdgcn_exp2f(s0.x - M);
  float w1 = __builtin_amdgcn_exp2f(s1.x - M);
  float inv = 1.0f / (s0.y * w0 + s1.y * w1);
  const float* p0 = Out + (size_t)q * DH + dc;
  const float* p1 = Op1 + (size_t)q * DH + dc;
  floatx4 a0 = *(const floatx4*)(p0);
  floatx4 a1 = *(const floatx4*)(p0 + 4);
  floatx4 b0 = *(const floatx4*)(p1);
  floatx4 b1 = *(const floatx4*)(p1 + 4);
  floatx4 r0 = (a0 * w0 + b0 * w1) * inv;
  floatx4 r1 = (a1 * w0 + b1 * w1) * inv;
  *(floatx4*)(Out + (size_t)q * DH + dc) = r0;
  *(floatx4*)(Out + (size_t)q * DH + dc + 4) = r1;
}

extern "C" void kernel_launch(void* const* d_in, const int* in_sizes, int n_in,
                              void* d_out, int out_size, void* d_ws, size_t ws_size,
                              hipStream_t stream) {
  const float* Q = (const float*)d_in[0];
  const float* K = (const float*)d_in[1];
  const float* V = (const float*)d_in[2];
  const int* mask = (const int*)d_in[3];
  float* Out = (float*)d_out;

  char* ws = (char*)d_ws;
  short*  Kb   = (short*)(ws);                          //  4 MB
  short*  Vt   = (short*)(ws + 4194304);                //  4 MB
  float*  bias = (float*)(ws + 8388608);                //  128 KB
  float2* ml   = (float2*)(ws + 8519680);               //  512 KB
  float*  Op1  = (float*)(ws + 9043968);                //  8 MB

  prepass  <<<KBLK + VBLK + BBLK, 256, 0, stream>>>(K, V, mask, Kb, Vt, bias);
  attn_main<<<2 * NB * (SQ / 64), 256, 0, stream>>>(Q, Kb, Vt, bias, Out, Op1, ml);
  combine  <<<NB * SQ * DH / 8 / 256, 256, 0, stream>>>(Op1, ml, Out);
}

// Round 7
// 121.068 us; speedup vs baseline: 1.0413x; 1.0413x over previous
//
#include <hip/hip_runtime.h>
#include <hip/hip_bf16.h>

#define NB 16
#define SQ 2048
#define SK 2048
#define DH 64

#define KBLK 1024      // prepass blocks for K convert
#define VBLK 512       // prepass blocks for V transpose
#define BBLK 128       // prepass blocks for bias

typedef __attribute__((ext_vector_type(8))) short short8;
typedef __attribute__((ext_vector_type(8))) __bf16 bf16x8;
typedef __attribute__((ext_vector_type(4))) float floatx4;
typedef __attribute__((ext_vector_type(16))) float floatx16;
typedef __attribute__((ext_vector_type(2))) unsigned uint2v;

__device__ __forceinline__ unsigned pk2(float a, float b) {
  __hip_bfloat162 h = __float22bfloat162_rn(make_float2(a, b));
  unsigned u; __builtin_memcpy(&u, &h, 4); return u;
}
__device__ __forceinline__ floatx16 mfma32(short8 a, short8 b, floatx16 c) {
  return __builtin_amdgcn_mfma_f32_32x32x16_bf16(
      __builtin_bit_cast(bf16x8, a), __builtin_bit_cast(bf16x8, b), c, 0, 0, 0);
}

// ---------- fused prepass: K->bf16, V->bf16 transposed tile-packed, mask->bias ----------
__global__ __launch_bounds__(256)
void prepass(const float* __restrict__ K, const float* __restrict__ V,
             const int* __restrict__ m, short* __restrict__ Kb,
             short* __restrict__ Vt, float* __restrict__ bias) {
  __shared__ unsigned tlw[64 * 33];   // [d][keypair], word-packed, +1 pad
  const int blk = blockIdx.x;
  const int t = threadIdx.x;
  if (blk < KBLK) {
    size_t i8 = ((size_t)blk * 256 + t) * 8;
    floatx4 a = *(const floatx4*)(K + i8);
    floatx4 b = *(const floatx4*)(K + i8 + 4);
    union { unsigned u[4]; short8 s; } w;
    w.u[0] = pk2(a[0], a[1]); w.u[1] = pk2(a[2], a[3]);
    w.u[2] = pk2(b[0], b[1]); w.u[3] = pk2(b[2], b[3]);
    *(short8*)(Kb + i8) = w.s;
  } else if (blk < KBLK + VBLK) {
    const int bt = blk - KBLK;            // b*32 + kt
    const int key2 = t & 31;              // key pair -> keys 2*key2, 2*key2+1
    const int dg = (t >> 5) * 8;          // 0,8,...,56
    const float* vp0 = V + ((size_t)bt * 64 + 2 * key2) * 64 + dg;
    const float* vp1 = vp0 + 64;
    floatx4 va  = *(const floatx4*)(vp0);
    floatx4 va2 = *(const floatx4*)(vp0 + 4);
    floatx4 vb  = *(const floatx4*)(vp1);
    floatx4 vb2 = *(const floatx4*)(vp1 + 4);
#pragma unroll
    for (int j = 0; j < 4; ++j) {
      tlw[(dg + j) * 33 + key2]     = pk2(va[j],  vb[j]);
      tlw[(dg + 4 + j) * 33 + key2] = pk2(va2[j], vb2[j]);
    }
    __syncthreads();
    const short* tls = (const short*)tlw;
    short* dst = Vt + (size_t)bt * 4096;
#pragma unroll
    for (int i = 0; i < 2; ++i) {
      int idx = i * 2048 + t * 8;          // flat [d][key]
      int d = idx >> 6, key = idx & 63;
      *(short8*)(dst + idx) = *(const short8*)(tls + d * 66 + key);
    }
  } else {
    int i = (blk - KBLK - VBLK) * 256 + t;
    bias[i] = m[i] ? -1e30f : 0.0f;
  }
}

// ---------- main: 32x32 MFMA flash attention, split-K x2, swizzled LDS ----------
__global__ __launch_bounds__(256)
void attn_main(const float* __restrict__ Q, const short* __restrict__ Kb,
               const short* __restrict__ Vt, const float* __restrict__ bias,
               float* __restrict__ Out, float* __restrict__ Op1,
               float2* __restrict__ ml) {
  __shared__ __align__(16) short ks[64 * 64];      // K tile [key][d], swizzled chunks
  __shared__ __align__(16) short vt[64 * 64];      // V^T tile [d][key], swizzled chunks
  __shared__ __align__(16) short pb[4 * 32 * 64];  // per-wave P [q][key], swizzled

  const int half = blockIdx.x >> 8;
  const int rest = blockIdx.x & 255;
  const int b    = rest >> 4;
  const int qt   = rest & 15;
  const int tid  = threadIdx.x;
  const int wave = tid >> 6;
  const int lane = tid & 63;
  const int n32  = lane & 31;     // this lane's query index within the wave's 32
  const int h    = lane >> 5;     // lane half
  const int sw   = n32 & 7;       // swizzle key for rows owned by this lane
  const int q0   = qt * 128 + wave * 32;
  const int kt0  = half << 4;

  // ---- Q B-fragments: qf[c] = Q[q0+n32][c*16+8h .. +7], scale*(log2 e) folded ----
  const float QS = 0.125f * 1.4426950408889634f;
  short8 qf[4];
  {
    const float* qp = Q + ((size_t)b * SQ + q0 + n32) * DH + 8 * h;
#pragma unroll
    for (int c = 0; c < 4; ++c) {
      floatx4 a  = *(const floatx4*)(qp + 16 * c);
      floatx4 a2 = *(const floatx4*)(qp + 16 * c + 4);
      union { unsigned u[4]; short8 s; } w;
      w.u[0] = pk2(a[0] * QS, a[1] * QS);
      w.u[1] = pk2(a[2] * QS, a[3] * QS);
      w.u[2] = pk2(a2[0] * QS, a2[1] * QS);
      w.u[3] = pk2(a2[2] * QS, a2[3] * QS);
      qf[c] = w.s;
    }
  }

  floatx16 o0, o1;
#pragma unroll
  for (int i = 0; i < 16; ++i) { o0[i] = 0.f; o1[i] = 0.f; }
  float m_q = -1e30f, l_q = 0.f;

  short* pw = pb + wave * 2048;

  const short* kg = Kb + (size_t)b * SK * DH;
  const short* vg = Vt + (size_t)b * 32 * 4096;
  const float* bg = bias + b * SK;

  // staging: thread writes rows (tid>>3) and 32+(tid>>3), chunk tid&7 (swizzled)
  const int srow  = tid >> 3;
  const int schk  = tid & 7;
  const int sphys = schk ^ (srow & 7);
  const int soff0 = srow * 64 + sphys * 8;
  const int soff1 = (srow + 32) * 64 + sphys * 8;
  const int goff0 = srow * 64 + schk * 8;
  const int goff1 = (srow + 32) * 64 + schk * 8;

  short8 kr[2], vr[2];
  {
    const short* kn = kg + (size_t)kt0 * 4096;
    const short* vn = vg + (size_t)kt0 * 4096;
    kr[0] = *(const short8*)(kn + goff0); kr[1] = *(const short8*)(kn + goff1);
    vr[0] = *(const short8*)(vn + goff0); vr[1] = *(const short8*)(vn + goff1);
  }

  for (int kt = kt0; kt < kt0 + 16; ++kt) {
    *(short8*)(ks + soff0) = kr[0]; *(short8*)(ks + soff1) = kr[1];
    *(short8*)(vt + soff0) = vr[0]; *(short8*)(vt + soff1) = vr[1];
    __syncthreads();

    if (kt + 1 < kt0 + 16) {
      const short* kn = kg + (size_t)(kt + 1) * 4096;
      const short* vn = vg + (size_t)(kt + 1) * 4096;
      kr[0] = *(const short8*)(kn + goff0); kr[1] = *(const short8*)(kn + goff1);
      vr[0] = *(const short8*)(vn + goff0); vr[1] = *(const short8*)(vn + goff1);
    }

    // ---- S^T = K Q^T : s0 = keys 0..31, s1 = keys 32..63 (D: key row, query col) ----
    floatx16 s0, s1;
#pragma unroll
    for (int i = 0; i < 16; ++i) { s0[i] = 0.f; s1[i] = 0.f; }
#pragma unroll
    for (int c = 0; c < 4; ++c) {
      short8 kf0 = *(short8*)(ks + n32 * 64        + ((2 * c + h) ^ sw) * 8);
      short8 kf1 = *(short8*)(ks + (32 + n32) * 64 + ((2 * c + h) ^ sw) * 8);
      s0 = mfma32(kf0, qf[c], s0);
      s1 = mfma32(kf1, qf[c], s1);
    }

    // ---- bias add + row max (key for s{g}[reg] = 32g + (reg&3) + 8*(reg>>2) + 4h) ----
    const float* bq = bg + kt * 64;
    float sc0[16], sc1[16];
    float rm = -1e30f;
#pragma unroll
    for (int u = 0; u < 4; ++u) {
      floatx4 bv0 = *(const floatx4*)(bq + 8 * u + 4 * h);
      floatx4 bv1 = *(const floatx4*)(bq + 32 + 8 * u + 4 * h);
#pragma unroll
      for (int i = 0; i < 4; ++i) {
        sc0[4 * u + i] = s0[4 * u + i] + bv0[i];
        sc1[4 * u + i] = s1[4 * u + i] + bv1[i];
        rm = fmaxf(rm, fmaxf(sc0[4 * u + i], sc1[4 * u + i]));
      }
    }
    rm = fmaxf(rm, __shfl_xor(rm, 32));
    float mn = fmaxf(m_q, rm);
    float alpha = __builtin_amdgcn_exp2f(m_q - mn);
    bool up = mn > m_q;
    m_q = mn;

    // ---- exp, pack, write P (row = query n32, col = 32g+8u+4h, swizzled) ----
    float rs = 0.f;
#pragma unroll
    for (int u = 0; u < 4; ++u) {
      float p0 = __builtin_amdgcn_exp2f(sc0[4 * u + 0] - mn);
      float p1 = __builtin_amdgcn_exp2f(sc0[4 * u + 1] - mn);
      float p2 = __builtin_amdgcn_exp2f(sc0[4 * u + 2] - mn);
      float p3 = __builtin_amdgcn_exp2f(sc0[4 * u + 3] - mn);
      rs += (p0 + p1) + (p2 + p3);
      uint2v w; w.x = pk2(p0, p1); w.y = pk2(p2, p3);
      *(uint2v*)(pw + n32 * 64 + (u ^ sw) * 8 + 4 * h) = w;

      float q0v = __builtin_amdgcn_exp2f(sc1[4 * u + 0] - mn);
      float q1v = __builtin_amdgcn_exp2f(sc1[4 * u + 1] - mn);
      float q2v = __builtin_amdgcn_exp2f(sc1[4 * u + 2] - mn);
      float q3v = __builtin_amdgcn_exp2f(sc1[4 * u + 3] - mn);
      rs += (q0v + q1v) + (q2v + q3v);
      uint2v w2; w2.x = pk2(q0v, q1v); w2.y = pk2(q2v, q3v);
      *(uint2v*)(pw + n32 * 64 + ((4 + u) ^ sw) * 8 + 4 * h) = w2;
    }
    rs += __shfl_xor(rs, 32);
    l_q = alpha * l_q + rs;

    if (__ballot(up)) {
#pragma unroll
      for (int i = 0; i < 16; ++i) { o0[i] *= alpha; o1[i] *= alpha; }
    }

    // ---- O^T += V^T P^T : A = V^T frags, B = P^T frags (in-lane query cols) ----
#pragma unroll
    for (int c = 0; c < 4; ++c) {
      short8 pf  = *(short8*)(pw + n32 * 64 + ((2 * c + h) ^ sw) * 8);
      short8 vf0 = *(short8*)(vt + n32 * 64        + ((2 * c + h) ^ sw) * 8);
      short8 vf1 = *(short8*)(vt + (32 + n32) * 64 + ((2 * c + h) ^ sw) * 8);
      o0 = mfma32(vf0, pf, o0);
      o1 = mfma32(vf1, pf, o1);
    }
    __syncthreads();
  }

  // ---- epilogue: O^T lane holds d = 32G+8u+4h+(0..3) for its own query ----
  float* Od = half ? Op1 : Out;
  float* orow = Od + ((size_t)b * SQ + q0 + n32) * DH;
#pragma unroll
  for (int u = 0; u < 4; ++u) {
    floatx4 w0, w1;
#pragma unroll
    for (int i = 0; i < 4; ++i) { w0[i] = o0[4 * u + i]; w1[i] = o1[4 * u + i]; }
    *(floatx4*)(orow + 8 * u + 4 * h)      = w0;
    *(floatx4*)(orow + 32 + 8 * u + 4 * h) = w1;
  }
  if (lane < 32)
    ml[(size_t)half * NB * SQ + (size_t)b * SQ + q0 + lane] = make_float2(m_q, l_q);
}

// ---------- combine the two split-K halves ----------
__global__ __launch_bounds__(256)
void combine(const float* __restrict__ Op1, const float2* __restrict__ ml,
             float* __restrict__ Out) {
  int idx = blockIdx.x * 256 + threadIdx.x;
  int q = idx >> 3;
  int dc = (idx & 7) * 8;
  float2 s0 = ml[q];
  float2 s1 = ml[NB * SQ + q];
  float M = fmaxf(s0.x, s1.x);
  float w0 = __builtin_amdgcn_exp2f(s0.x - M);
  float w1 = __builtin_amdgcn_exp2f(s1.x - M);
  float inv = 1.0f / (s0.y * w0 + s1.y * w1);
  const float* p0 = Out + (size_t)q * DH + dc;
  const float* p1 = Op1 + (size_t)q * DH + dc;
  floatx4 a0 = *(const floatx4*)(p0);
  floatx4 a1 = *(const floatx4*)(p0 + 4);
  floatx4 b0 = *(const floatx4*)(p1);
  floatx4 b1 = *(const floatx4*)(p1 + 4);
  floatx4 r0 = (a0 * w0 + b0 * w1) * inv;
  floatx4 r1 = (a1 * w0 + b1 * w1) * inv;
  *(floatx4*)(Out + (size_t)q * DH + dc) = r0;
  *(floatx4*)(Out + (size_t)q * DH + dc + 4) = r1;
}

extern "C" void kernel_launch(void* const* d_in, const int* in_sizes, int n_in,
                              void* d_out, int out_size, void* d_ws, size_t ws_size,
                              hipStream_t stream) {
  const float* Q = (const float*)d_in[0];
  const float* K = (const float*)d_in[1];
  const float* V = (const float*)d_in[2];
  const int* mask = (const int*)d_in[3];
  float* Out = (float*)d_out;

  char* ws = (char*)d_ws;
  short*  Kb   = (short*)(ws);                          //  4 MB
  short*  Vt   = (short*)(ws + 4194304);                //  4 MB
  float*  bias = (float*)(ws + 8388608);                //  128 KB
  float2* ml   = (float2*)(ws + 8519680);               //  512 KB
  float*  Op1  = (float*)(ws + 9043968);                //  8 MB

  prepass  <<<KBLK + VBLK + BBLK, 256, 0, stream>>>(K, V, mask, Kb, Vt, bias);
  attn_main<<<2 * NB * (SQ / 128), 256, 0, stream>>>(Q, Kb, Vt, bias, Out, Op1, ml);
  combine  <<<NB * SQ * DH / 8 / 256, 256, 0, stream>>>(Op1, ml, Out);
}